// Round 16
// baseline (148.605 us; speedup 1.0000x reference)
//
#include <hip/hip_runtime.h>

#define NROWS 1000000
#define NB    3907          // ceil(1e6 / 256) mask blocks
#define NT    62500         // 16-row tiles
#define GROUPS 15625        // 4-tile groups (exact: 62500/4)
#define MLP_BLOCKS 512      // persistent: 2 blocks/CU at VGPR<=128, LDS=0

typedef __bf16 bf16x8 __attribute__((ext_vector_type(8)));
typedef float  f32x4  __attribute__((ext_vector_type(4)));

// f32 pair -> packed bf16 (RNE), 1 instr (T12 recipe; gfx950 has no builtin)
__device__ __forceinline__ unsigned cvt_pk_bf16(float lo, float hi) {
  unsigned r;
  asm("v_cvt_pk_bf16_f32 %0, %1, %2" : "=v"(r) : "v"(lo), "v"(hi));
  return r;
}

// ---------------------------------------------------------------------------
// Kernel 1: per-256-row-block nonzero counts (3907 sums).
// ---------------------------------------------------------------------------
__global__ __launch_bounds__(256) void count_kernel(
    const int* __restrict__ mask, int* __restrict__ bsum) {
  int tid = threadIdx.x;
  int row = blockIdx.x * 256 + tid;
  int cnt = 0;
  if (row < NROWS) {
    const int4* mp = (const int4*)(mask + (long)row * 8);
    int4 a = mp[0], b = mp[1];
    cnt = (a.x != 0) + (a.y != 0) + (a.z != 0) + (a.w != 0) +
          (b.x != 0) + (b.y != 0) + (b.z != 0) + (b.w != 0);
  }
#pragma unroll
  for (int off = 1; off < 64; off <<= 1) cnt += __shfl_xor(cnt, off);
  __shared__ int ws[4];
  if ((tid & 63) == 0) ws[tid >> 6] = cnt;
  __syncthreads();
  if (tid == 0) bsum[blockIdx.x] = ws[0] + ws[1] + ws[2] + ws[3];
}

// ---------------------------------------------------------------------------
// Kernel 2: exclusive scan of 3907 block sums (single block).
// ---------------------------------------------------------------------------
__global__ __launch_bounds__(1024) void scan_kernel(
    const int* __restrict__ bsum, int* __restrict__ boff) {
  __shared__ int lds[1024];
  int t = threadIdx.x;
  int i0 = t * 4;
  int c0 = (i0 + 0 < NB) ? bsum[i0 + 0] : 0;
  int c1 = (i0 + 1 < NB) ? bsum[i0 + 1] : 0;
  int c2 = (i0 + 2 < NB) ? bsum[i0 + 2] : 0;
  int c3 = (i0 + 3 < NB) ? bsum[i0 + 3] : 0;
  int s = c0 + c1 + c2 + c3;
  lds[t] = s;
  __syncthreads();
  for (int off = 1; off < 1024; off <<= 1) {
    int v = lds[t];
    int add = (t >= off) ? lds[t - off] : 0;
    __syncthreads();
    lds[t] = v + add;
    __syncthreads();
  }
  int excl = lds[t] - s;
  if (i0 + 0 < NB) boff[i0 + 0] = excl;
  excl += c0;
  if (i0 + 1 < NB) boff[i0 + 1] = excl;
  excl += c1;
  if (i0 + 2 < NB) boff[i0 + 2] = excl;
  excl += c2;
  if (i0 + 3 < NB) boff[i0 + 3] = excl;
}

// ---------------------------------------------------------------------------
// Kernel 3: per-row info = (scatter_pos << 8) | mask_bits.
// ---------------------------------------------------------------------------
__global__ __launch_bounds__(256) void expand_kernel(
    const int* __restrict__ mask, const int* __restrict__ boff,
    int* __restrict__ rowinfo) {
  int tid = threadIdx.x;
  int row = blockIdx.x * 256 + tid;
  bool valid = row < NROWS;
  unsigned mb = 0;
  int cnt = 0;
  if (valid) {
    const int4* mp = (const int4*)(mask + (long)row * 8);
    int4 a = mp[0], b = mp[1];
    mb = (unsigned)((a.x != 0) | ((a.y != 0) << 1) | ((a.z != 0) << 2) |
                    ((a.w != 0) << 3) | ((b.x != 0) << 4) | ((b.y != 0) << 5) |
                    ((b.z != 0) << 6) | ((b.w != 0) << 7));
    cnt = __popc(mb);
  }
  int incl = cnt;
#pragma unroll
  for (int off = 1; off < 64; off <<= 1) {
    int v = __shfl_up(incl, off);
    if ((tid & 63) >= off) incl += v;
  }
  __shared__ int wsum[4];
  if ((tid & 63) == 63) wsum[tid >> 6] = incl;
  __syncthreads();
  int w = tid >> 6;
  int wo = 0;
  if (w > 0) wo += wsum[0];
  if (w > 1) wo += wsum[1];
  if (w > 2) wo += wsum[2];
  int pos = boff[blockIdx.x] + wo + (incl - cnt);
  if (valid) rowinfo[row] = (pos << 8) | (int)mb;
}

// ---------------------------------------------------------------------------
// Kernel 4: head-per-wave MFMA MLP, zero LDS, persistent blocks.
//   Wave w owns head hp=w. All W0/b0/w1/b1 fragments in registers (one-time
//   staging). Per 4-tile group: 8 dwordx4 x-loads (L1-shared across the 8
//   waves of the block), 4x {4 indep L0 MFMA -> cvt -> 2 chained L1 MFMA ->
//   immediate scatter via rowinfo (pos computable per (row,d) independently)}.
//   Fragment formulas identical to the R8-verified kernel.
// ---------------------------------------------------------------------------
__global__ __launch_bounds__(512, 4) void mlp_kernel(
    const float* __restrict__ x, const float* __restrict__ w0,
    const float* __restrict__ b0, const float* __restrict__ w1,
    const float* __restrict__ b1, const int* __restrict__ rowinfo,
    float* __restrict__ out) {
  int tid = threadIdx.x;
  int hp = tid >> 6;        // head 0..7 (one per wave)
  int l = tid & 63;
  int n = l & 15;           // MFMA col / row-in-tile
  int g = l >> 4;           // 16-lane group (k-chunk; D-row group)

  // ---- one-time register staging (per block lifetime) ----
  // W0^T fragments: frag qb, lane (g,n): q = qb*16+n, k = g*8+j
  bf16x8 A0f, A1f, A2f, A3f;
#define LDA(QB, DST) {                                              \
    const float* wp = w0 + hp * 2048 + (g * 8) * 64 + QB * 16 + n;  \
    _Pragma("unroll")                                               \
    for (int j = 0; j < 8; ++j) DST[j] = (__bf16)wp[j * 64];        }
  LDA(0, A0f) LDA(1, A1f) LDA(2, A2f) LDA(3, A3f)
#undef LDA
  // b0 fragments in D pattern: Cqb[r] = b0[hp*64 + qb*16 + g*4 + r]
  f32x4 C0 = *(const f32x4*)&b0[hp * 64 + 0 * 16 + g * 4];
  f32x4 C1 = *(const f32x4*)&b0[hp * 64 + 1 * 16 + g * 4];
  f32x4 C2 = *(const f32x4*)&b0[hp * 64 + 2 * 16 + g * 4];
  f32x4 C3 = *(const f32x4*)&b0[hp * 64 + 3 * 16 + g * 4];
  // w1 fragments (values wave-uniform; masked to A2-row m == hp)
  bf16x8 w1a, w1b;
#pragma unroll
  for (int j = 0; j < 8; ++j) {
    int off = (j >> 2) * 16 + g * 4 + (j & 3);  // k-slot -> hidden (verified)
    w1a[j] = (__bf16)w1[hp * 64 + off];
    w1b[j] = (__bf16)w1[hp * 64 + 32 + off];
  }
  bool own = (n == hp);
  int4 z4 = {0, 0, 0, 0};
  int4 tAa = own ? *(int4*)&w1a : z4;
  int4 tAb = own ? *(int4*)&w1b : z4;
  bf16x8 A2a = *(bf16x8*)&tAa;
  bf16x8 A2b = *(bf16x8*)&tAb;
  f32x4 b1C;
#pragma unroll
  for (int r = 0; r < 4; ++r) b1C[r] = b1[(g * 4 + r) & 7];

  int sg = hp >> 2;         // store lane-group
  int sr = hp & 3;          // store reg index (wave-uniform)
  unsigned dmask = (1u << hp) - 1u;

  for (int gq = blockIdx.x; gq < GROUPS; gq += MLP_BLOCKS) {
    int t0 = gq * 4;

    // ---- x fragments for 4 tiles ----
    bf16x8 xf0, xf1, xf2, xf3;
    {
      const float* xp;
      float4 a, c;
      uint4 ui;
#define LOADX(T, DST)                                              \
      xp = x + (long)((t0 + T) * 16 + n) * 32 + g * 8;             \
      a = *(const float4*)xp; c = *(const float4*)(xp + 4);        \
      ui.x = cvt_pk_bf16(a.x, a.y); ui.y = cvt_pk_bf16(a.z, a.w);  \
      ui.z = cvt_pk_bf16(c.x, c.y); ui.w = cvt_pk_bf16(c.z, c.w);  \
      DST = *(bf16x8*)&ui;
      LOADX(0, xf0) LOADX(1, xf1) LOADX(2, xf2) LOADX(3, xf3)
#undef LOADX
    }

#define TILE(T, XF) {                                                         \
      f32x4 D0 = __builtin_amdgcn_mfma_f32_16x16x32_bf16(A0f, XF, C0, 0,0,0); \
      f32x4 D1 = __builtin_amdgcn_mfma_f32_16x16x32_bf16(A1f, XF, C1, 0,0,0); \
      f32x4 D2 = __builtin_amdgcn_mfma_f32_16x16x32_bf16(A2f, XF, C2, 0,0,0); \
      f32x4 D3 = __builtin_amdgcn_mfma_f32_16x16x32_bf16(A3f, XF, C3, 0,0,0); \
      uint4 bu;                                                               \
      bu.x = cvt_pk_bf16(fmaxf(D0[0], 0.f), fmaxf(D0[1], 0.f));               \
      bu.y = cvt_pk_bf16(fmaxf(D0[2], 0.f), fmaxf(D0[3], 0.f));               \
      bu.z = cvt_pk_bf16(fmaxf(D1[0], 0.f), fmaxf(D1[1], 0.f));               \
      bu.w = cvt_pk_bf16(fmaxf(D1[2], 0.f), fmaxf(D1[3], 0.f));               \
      bf16x8 B2 = *(bf16x8*)&bu;                                              \
      uint4 bv;                                                               \
      bv.x = cvt_pk_bf16(fmaxf(D2[0], 0.f), fmaxf(D2[1], 0.f));               \
      bv.y = cvt_pk_bf16(fmaxf(D2[2], 0.f), fmaxf(D2[3], 0.f));               \
      bv.z = cvt_pk_bf16(fmaxf(D3[0], 0.f), fmaxf(D3[1], 0.f));               \
      bv.w = cvt_pk_bf16(fmaxf(D3[2], 0.f), fmaxf(D3[3], 0.f));               \
      bf16x8 B3 = *(bf16x8*)&bv;                                              \
      f32x4 O = __builtin_amdgcn_mfma_f32_16x16x32_bf16(A2a, B2, b1C, 0,0,0); \
      O = __builtin_amdgcn_mfma_f32_16x16x32_bf16(A2b, B3, O, 0, 0, 0);       \
      if (g == sg) {                                                          \
        int row = (t0 + T) * 16 + n;                                          \
        int info = rowinfo[row];                                              \
        unsigned mb = (unsigned)info & 255u;                                  \
        if ((mb >> hp) & 1u) {                                                \
          int pos = (int)(((unsigned)info) >> 8) + __popc(mb & dmask);        \
          float v = (sr == 0) ? O[0]                                          \
                  : (sr == 1) ? O[1]                                          \
                  : (sr == 2) ? O[2] : O[3];                                  \
          out[pos] = v;                                                       \
        }                                                                     \
      }                                                                       }
    TILE(0, xf0) TILE(1, xf1) TILE(2, xf2) TILE(3, xf3)
#undef TILE
  }
}

extern "C" void kernel_launch(void* const* d_in, const int* in_sizes, int n_in,
                              void* d_out, int out_size, void* d_ws, size_t ws_size,
                              hipStream_t stream) {
  const float* x    = (const float*)d_in[0];
  const int*   mask = (const int*)d_in[1];
  const float* w0   = (const float*)d_in[2];
  const float* b0   = (const float*)d_in[3];
  const float* w1   = (const float*)d_in[4];
  const float* b1   = (const float*)d_in[5];
  float* out = (float*)d_out;

  int* bsum    = (int*)d_ws;
  int* boff    = bsum + NB;
  int* rowinfo = boff + NB;

  count_kernel<<<NB, 256, 0, stream>>>(mask, bsum);
  scan_kernel<<<1, 1024, 0, stream>>>(bsum, boff);
  expand_kernel<<<NB, 256, 0, stream>>>(mask, boff, rowinfo);
  mlp_kernel<<<MLP_BLOCKS, 512, 0, stream>>>(x, w0, b0, w1, b1, rowinfo, out);
}